// Round 2
// baseline (465.748 us; speedup 1.0000x reference)
//
#include <hip/hip_runtime.h>

typedef unsigned long long u64;
typedef unsigned int u32;

#define N1 4096
#define N2 2048
#define NT 6144
#define CAP 4096
#define IMG 1280.0f
#define MATCH_IOU_T 0.8f
#define NMS_IOU_T 0.95f

// IoU with exact op-order mirroring of the reference (no FMA contraction).
__device__ __forceinline__ float iou_f(const float* a, const float* b) {
    float x1 = fmaxf(a[0], b[0]);
    float y1 = fmaxf(a[1], b[1]);
    float x2 = fminf(a[2], b[2]);
    float y2 = fminf(a[3], b[3]);
    float dx = fmaxf(__fsub_rn(x2, x1), 0.0f);
    float dy = fmaxf(__fsub_rn(y2, y1), 0.0f);
    float inter = __fmul_rn(dx, dy);
    float a1 = __fmul_rn(__fsub_rn(a[2], a[0]), __fsub_rn(a[3], a[1]));
    float a2 = __fmul_rn(__fsub_rn(b[2], b[0]), __fsub_rn(b[3], b[1]));
    float den = __fsub_rn(__fadd_rn(a1, a2), inter);
    return __fdiv_rn(inter, den);
}

// K0: normalize frcnn boxes, weight scores, zero pair counter.
__global__ void k0_prep(const float* fb, const float* fs, float* b2n, float* s2w, int* pcount) {
    int t = blockIdx.x * blockDim.x + threadIdx.x;
    if (t < N2 * 4) b2n[t] = __fdiv_rn(fb[t], IMG);
    if (t < N2)     s2w[t] = __fmul_rn(fs[t], 0.5f);
    if (t == 0)     *pcount = 0;
}

// K1: per yolo box i, flag if ANY same-label frcnn box has IoU >= 0.8
// (ignoring `used` — masking can only lower IoU, so unflagged i provably
// cannot merge). Also write default (unmerged) mbox/mscore.
__global__ void __launch_bounds__(256) k1_flag(const float* yb, const float* ys,
                                               const int* yl, const int* fl,
                                               const float* b2n, float* mbox,
                                               float* mscore, int* flag) {
    int i = blockIdx.x;
    int tid = threadIdx.x;
    float a[4];
#pragma unroll
    for (int c = 0; c < 4; c++) a[c] = __fdiv_rn(yb[i * 4 + c], IMG);
    int lab = yl[i];
    bool any = false;
    for (int j = tid; j < N2; j += 256) {
        if (fl[j] == lab) {
            float bb[4] = {b2n[j * 4], b2n[j * 4 + 1], b2n[j * 4 + 2], b2n[j * 4 + 3]};
            if (iou_f(a, bb) >= MATCH_IOU_T) any = true;
        }
    }
    __shared__ int anyw[4];
    u64 m = __ballot(any);
    if ((tid & 63) == 0) anyw[tid >> 6] = (m != 0ULL) ? 1 : 0;
    __syncthreads();
    if (tid == 0) {
        flag[i] = anyw[0] | anyw[1] | anyw[2] | anyw[3];
#pragma unroll
        for (int c = 0; c < 4; c++) mbox[i * 4 + c] = a[c];
        mscore[i] = __fmul_rn(ys[i], 0.5f);
    }
}

// K2: exact sequential greedy matching over only the flagged rows.
// Single block; masked argmax over 2048 frcnn boxes parallelized across 256
// threads; `used` carried in LDS. Tie-break = lowest j (argmax semantics).
__global__ void __launch_bounds__(256) k2_match(const int* yl, const int* fl,
                                                const float* b2n, const float* s2w,
                                                const int* flag, float* mbox,
                                                float* mscore, int* valid2) {
    __shared__ unsigned char used[N2];
    __shared__ unsigned char flg[N1];
    __shared__ unsigned short list[N1];
    __shared__ int cnt;
    __shared__ float rv[256];
    __shared__ int ri[256];
    int tid = threadIdx.x;
    for (int j = tid; j < N2; j += 256) used[j] = 0;
    for (int i = tid; i < N1; i += 256) flg[i] = (unsigned char)(flag[i] != 0);
    __syncthreads();
    if (tid == 0) {
        int c = 0;
        for (int i = 0; i < N1; i++)
            if (flg[i]) list[c++] = (unsigned short)i;
        cnt = c;
    }
    __syncthreads();
    int c = cnt;
    for (int p = 0; p < c; p++) {
        int i = list[p];
        float a[4];
#pragma unroll
        for (int cc = 0; cc < 4; cc++) a[cc] = mbox[i * 4 + cc];
        float sc = mscore[i];
        int lab = yl[i];
        float bv = -1.0f;
        int bi = 1 << 30;
        for (int j = tid; j < N2; j += 256) {
            float v = 0.0f;
            if (!used[j] && fl[j] == lab) {
                float bb[4] = {b2n[j * 4], b2n[j * 4 + 1], b2n[j * 4 + 2], b2n[j * 4 + 3]};
                v = iou_f(a, bb);
            }
            if (v > bv || (v == bv && j < bi)) { bv = v; bi = j; }
        }
        rv[tid] = bv; ri[tid] = bi;
        __syncthreads();
        for (int s = 128; s > 0; s >>= 1) {
            if (tid < s) {
                float ov = rv[tid + s]; int oi = ri[tid + s];
                if (ov > rv[tid] || (ov == rv[tid] && oi < ri[tid])) { rv[tid] = ov; ri[tid] = oi; }
            }
            __syncthreads();
        }
        if (tid == 0 && rv[0] >= MATCH_IOU_T) {
            int j = ri[0];
            float s2 = s2w[j];
            float tot = __fadd_rn(sc, s2);
#pragma unroll
            for (int cc = 0; cc < 4; cc++) {
                float merged = __fdiv_rn(
                    __fadd_rn(__fmul_rn(a[cc], sc), __fmul_rn(b2n[j * 4 + cc], s2)), tot);
                mbox[i * 4 + cc] = merged;
            }
            mscore[i] = tot;
            used[j] = 1;
        }
        __syncthreads();
    }
    for (int j = tid; j < N2; j += 256) valid2[j] = used[j] ? 0 : 1;
}

// K3: composite sort keys. Stable argsort(-where(valid,s,-1)) == ascending
// sort of ((~sortable_f32(val)) << 32) | index.
__global__ void k3_keys(const float* mscore, const float* s2w, const int* valid2, u64* keys) {
    int i = blockIdx.x * blockDim.x + threadIdx.x;
    if (i >= NT) return;
    float sc; int val;
    if (i < N1) { sc = mscore[i]; val = 1; }
    else        { sc = s2w[i - N1]; val = valid2[i - N1]; }
    float f = val ? sc : -1.0f;
    u32 u = __float_as_uint(f);
    u32 asc = (u >> 31) ? ~u : (u | 0x80000000u);
    keys[i] = (((u64)(~asc)) << 32) | (u32)i;
}

// K4: exact stable sort by rank-counting (keys unique -> perfect permutation).
__global__ void __launch_bounds__(256) k4_rank(const u64* keys, int* ord) {
    int i = blockIdx.x;
    u64 my = keys[i];
    int tid = threadIdx.x;
    int cnt = 0;
    for (int j = tid; j < NT; j += 256) cnt += (keys[j] < my) ? 1 : 0;
    __shared__ int r[256];
    r[tid] = cnt;
    __syncthreads();
    for (int s = 128; s > 0; s >>= 1) { if (tid < s) r[tid] += r[tid + s]; __syncthreads(); }
    if (tid == 0) ord[r[0]] = i;
}

// K5: gather into sorted order; write boxes/labels/scores outputs.
__global__ void k5_gather(const int* ord, const float* mbox, const float* mscore,
                          const float* b2n, const float* s2w, const int* valid2,
                          const int* yl, const int* fl,
                          float* sboxn, int* slab, int* svalid, float* out) {
    int k = blockIdx.x * blockDim.x + threadIdx.x;
    if (k >= NT) return;
    int i = ord[k];
    float b[4]; int lab; float sc; int val;
    if (i < N1) {
#pragma unroll
        for (int c = 0; c < 4; c++) b[c] = mbox[i * 4 + c];
        lab = yl[i]; sc = mscore[i]; val = 1;
    } else {
        int j = i - N1;
#pragma unroll
        for (int c = 0; c < 4; c++) b[c] = b2n[j * 4 + c];
        lab = fl[j]; sc = s2w[j]; val = valid2[j];
    }
#pragma unroll
    for (int c = 0; c < 4; c++) {
        sboxn[k * 4 + c] = b[c];
        out[k * 4 + c] = __fmul_rn(b[c], IMG);
    }
    slab[k] = lab; svalid[k] = val;
    out[24576 + k] = (lab == 0) ? 2.0f : 1.0f;   // label_map[clip(l,0,1)]
    out[24576 + NT + k] = sc;                     // sorted scores
}

// K6: NMS candidate pairs (i<j, same label, IoU >= 0.95) -> atomic append.
__global__ void __launch_bounds__(256) k6_pairs(const float* sboxn, const int* slab,
                                                int* pcount, u64* pairs) {
    int i = blockIdx.x;
    int tid = threadIdx.x;
    float a[4] = {sboxn[i * 4], sboxn[i * 4 + 1], sboxn[i * 4 + 2], sboxn[i * 4 + 3]};
    int lab = slab[i];
    for (int j = i + 1 + tid; j < NT; j += 256) {
        if (slab[j] == lab) {
            float bb[4] = {sboxn[j * 4], sboxn[j * 4 + 1], sboxn[j * 4 + 2], sboxn[j * 4 + 3]};
            if (iou_f(a, bb) >= NMS_IOU_T) {
                int pos = atomicAdd(pcount, 1);
                if (pos < CAP) pairs[pos] = (((u64)(u32)i) << 32) | (u32)j;
            }
        }
    }
}

// K7: sort pairs (restores determinism after atomic append), then exact
// sequential suppression resolution; write keep mask.
__global__ void __launch_bounds__(256) k7_resolve(const int* pcount, const u64* pairs,
                                                  const int* svalid, float* out) {
    __shared__ u64 pl[CAP];
    __shared__ unsigned char sup[NT];
    int tid = threadIdx.x;
    int np = *pcount;
    if (np > CAP) np = CAP;
    for (int t = tid; t < CAP; t += 256) pl[t] = (t < np) ? pairs[t] : ~0ULL;
    for (int k = tid; k < NT; k += 256) sup[k] = svalid[k] ? 0 : 1;
    __syncthreads();
    // bitonic sort of CAP u64 keys in LDS
    for (int k2 = 2; k2 <= CAP; k2 <<= 1) {
        for (int jj = k2 >> 1; jj > 0; jj >>= 1) {
            for (int idx = tid; idx < CAP; idx += 256) {
                int l = idx ^ jj;
                if (l > idx) {
                    u64 A = pl[idx], B = pl[l];
                    bool up = ((idx & k2) == 0);
                    if (up ? (A > B) : (A < B)) { pl[idx] = B; pl[l] = A; }
                }
            }
            __syncthreads();
        }
    }
    if (tid == 0) {
        for (int p = 0; p < np; p++) {
            u64 pr = pl[p];
            int i = (int)(pr >> 32);
            int j = (int)(pr & 0xffffffffu);
            if (!sup[i]) sup[j] = 1;
        }
    }
    __syncthreads();
    for (int k = tid; k < NT; k += 256) out[24576 + 2 * NT + k] = sup[k] ? 0.0f : 1.0f;
}

extern "C" void kernel_launch(void* const* d_in, const int* in_sizes, int n_in,
                              void* d_out, int out_size, void* d_ws, size_t ws_size,
                              hipStream_t stream) {
    const float* yb = (const float*)d_in[0];
    const float* ys = (const float*)d_in[1];
    const int*   yl = (const int*)d_in[2];
    const float* fb = (const float*)d_in[3];
    const float* fs = (const float*)d_in[4];
    const int*   fl = (const int*)d_in[5];
    float* out = (float*)d_out;
    char* ws = (char*)d_ws;

    float* b2n    = (float*)(ws);            // 2048*4 f   = 32768 B
    float* s2w    = (float*)(ws + 32768);    // 2048 f     =  8192 B
    float* mbox   = (float*)(ws + 40960);    // 4096*4 f   = 65536 B
    float* mscore = (float*)(ws + 106496);   // 4096 f     = 16384 B
    int*   flag   = (int*)  (ws + 122880);   // 4096 i     = 16384 B
    int*   valid2 = (int*)  (ws + 139264);   // 2048 i     =  8192 B
    u64*   keys   = (u64*)  (ws + 147456);   // 6144 u64   = 49152 B
    int*   ord    = (int*)  (ws + 196608);   // 6144 i     = 24576 B
    float* sboxn  = (float*)(ws + 221184);   // 6144*4 f   = 98304 B
    int*   slab   = (int*)  (ws + 319488);   // 6144 i     = 24576 B
    int*   svalid = (int*)  (ws + 344064);   // 6144 i     = 24576 B
    int*   pcount = (int*)  (ws + 368640);   // 8 B
    u64*   pairs  = (u64*)  (ws + 368648);   // 4096 u64   = 32768 B  (end ~401 KB)

    hipLaunchKernelGGL(k0_prep,  dim3(32),  dim3(256), 0, stream, fb, fs, b2n, s2w, pcount);
    hipLaunchKernelGGL(k1_flag,  dim3(N1),  dim3(256), 0, stream, yb, ys, yl, fl, b2n, mbox, mscore, flag);
    hipLaunchKernelGGL(k2_match, dim3(1),   dim3(256), 0, stream, yl, fl, b2n, s2w, flag, mbox, mscore, valid2);
    hipLaunchKernelGGL(k3_keys,  dim3(24),  dim3(256), 0, stream, mscore, s2w, valid2, keys);
    hipLaunchKernelGGL(k4_rank,  dim3(NT),  dim3(256), 0, stream, keys, ord);
    hipLaunchKernelGGL(k5_gather,dim3(24),  dim3(256), 0, stream, ord, mbox, mscore, b2n, s2w, valid2, yl, fl, sboxn, slab, svalid, out);
    hipLaunchKernelGGL(k6_pairs, dim3(NT),  dim3(256), 0, stream, sboxn, slab, pcount, pairs);
    hipLaunchKernelGGL(k7_resolve,dim3(1),  dim3(256), 0, stream, pcount, pairs, svalid, out);
}

// Round 6
// 119.220 us; speedup vs baseline: 3.9066x; 3.9066x over previous
//
#include <hip/hip_runtime.h>

typedef unsigned long long u64;
typedef unsigned int u32;

#define N1 4096
#define N2 2048
#define NT 6144
#define CAP 4096
#define IMG 1280.0f
#define MATCH_IOU_T 0.8f
#define NMS_IOU_T 0.95f

// IoU with exact op-order mirroring of the reference (no FMA contraction).
__device__ __forceinline__ float iou_f(const float* a, const float* b) {
    float x1 = fmaxf(a[0], b[0]);
    float y1 = fmaxf(a[1], b[1]);
    float x2 = fminf(a[2], b[2]);
    float y2 = fminf(a[3], b[3]);
    float dx = fmaxf(__fsub_rn(x2, x1), 0.0f);
    float dy = fmaxf(__fsub_rn(y2, y1), 0.0f);
    float inter = __fmul_rn(dx, dy);
    float a1 = __fmul_rn(__fsub_rn(a[2], a[0]), __fsub_rn(a[3], a[1]));
    float a2 = __fmul_rn(__fsub_rn(b[2], b[0]), __fsub_rn(b[3], b[1]));
    float den = __fsub_rn(__fadd_rn(a1, a2), inter);
    return __fdiv_rn(inter, den);
}

// K0: normalize frcnn boxes, weight scores, zero pair counter.
__global__ void k0_prep(const float* fb, const float* fs, float* b2n, float* s2w, int* pcount) {
    int t = blockIdx.x * blockDim.x + threadIdx.x;
    if (t < N2 * 4) b2n[t] = __fdiv_rn(fb[t], IMG);
    if (t < N2)     s2w[t] = __fmul_rn(fs[t], 0.5f);
    if (t == 0)     *pcount = 0;
}

// K1: per yolo box i, flag if ANY same-label frcnn box has IoU >= 0.8
// (ignoring `used` — masking can only lower IoU, so unflagged i provably
// cannot merge). Also write default (unmerged) mbox/mscore.
__global__ void __launch_bounds__(256) k1_flag(const float* yb, const float* ys,
                                               const int* yl, const int* fl,
                                               const float* b2n, float* mbox,
                                               float* mscore, int* flag) {
    int i = blockIdx.x;
    int tid = threadIdx.x;
    float a[4];
#pragma unroll
    for (int c = 0; c < 4; c++) a[c] = __fdiv_rn(yb[i * 4 + c], IMG);
    int lab = yl[i];
    bool any = false;
    for (int j = tid; j < N2; j += 256) {
        if (fl[j] == lab) {
            float bb[4] = {b2n[j * 4], b2n[j * 4 + 1], b2n[j * 4 + 2], b2n[j * 4 + 3]};
            if (iou_f(a, bb) >= MATCH_IOU_T) any = true;
        }
    }
    __shared__ int anyw[4];
    u64 m = __ballot(any);
    if ((tid & 63) == 0) anyw[tid >> 6] = (m != 0ULL) ? 1 : 0;
    __syncthreads();
    if (tid == 0) {
        flag[i] = anyw[0] | anyw[1] | anyw[2] | anyw[3];
#pragma unroll
        for (int c = 0; c < 4; c++) mbox[i * 4 + c] = a[c];
        mscore[i] = __fmul_rn(ys[i], 0.5f);
    }
}

// K2: exact sequential greedy matching over only the flagged rows.
// Parallel prefix-scan compaction of flags (was: thread-0 serial loop — 269us
// of dependent-latency, the round-2 bottleneck). b2n/fl staged in LDS once;
// per-candidate masked argmax uses wave64 shfl reduce (2 barriers/iter).
__global__ void __launch_bounds__(256) k2_match(const int* yl, const int* fl,
                                                const float* b2n, const float* s2w,
                                                const int* flag, float* mbox,
                                                float* mscore, int* valid2) {
    __shared__ unsigned char used[N2];
    __shared__ unsigned char fl_s[N2];
    __shared__ float b2s[N2 * 4];          // 32 KB
    __shared__ unsigned short list[N1];    // 8 KB
    __shared__ int sc_s[256];
    __shared__ int cnt_s;
    __shared__ float rv[4];
    __shared__ int ri[4];
    int tid = threadIdx.x;
    for (int j = tid; j < N2; j += 256) { used[j] = 0; fl_s[j] = (unsigned char)fl[j]; }
    for (int t = tid; t < N2 * 4; t += 256) b2s[t] = b2n[t];
    // --- parallel ordered compaction of flag[] into list[] ---
    unsigned short loc[16];
    int base = tid * 16, c = 0;
#pragma unroll
    for (int k = 0; k < 16; k++) {
        int i = base + k;
        if (flag[i]) loc[c++] = (unsigned short)i;
    }
    sc_s[tid] = c;
    __syncthreads();
    for (int s = 1; s < 256; s <<= 1) {
        int v = sc_s[tid];
        int o = (tid >= s) ? sc_s[tid - s] : 0;
        __syncthreads();
        sc_s[tid] = v + o;
        __syncthreads();
    }
    int excl = sc_s[tid] - c;
    for (int k = 0; k < c; k++) list[excl + k] = loc[k];
    if (tid == 255) cnt_s = sc_s[255];
    __syncthreads();
    int cnt = cnt_s;
    // --- sequential greedy over flagged rows (cnt is tiny) ---
    for (int p = 0; p < cnt; p++) {
        int i = list[p];
        float a[4];
#pragma unroll
        for (int cc = 0; cc < 4; cc++) a[cc] = mbox[i * 4 + cc];  // broadcast
        int lab = yl[i];
        float bv = -1.0f;
        int bi = 1 << 30;
        for (int j = tid; j < N2; j += 256) {
            float v = 0.0f;
            if (!used[j] && fl_s[j] == (unsigned char)lab) {
                float bb[4] = {b2s[j * 4], b2s[j * 4 + 1], b2s[j * 4 + 2], b2s[j * 4 + 3]};
                v = iou_f(a, bb);
            }
            if (v > bv || (v == bv && j < bi)) { bv = v; bi = j; }
        }
        // wave64 argmax reduce (max v, tie-break lowest j)
#pragma unroll
        for (int s = 32; s > 0; s >>= 1) {
            float ov = __shfl_down(bv, s, 64);
            int oi = __shfl_down(bi, s, 64);
            if (ov > bv || (ov == bv && oi < bi)) { bv = ov; bi = oi; }
        }
        if ((tid & 63) == 0) { rv[tid >> 6] = bv; ri[tid >> 6] = bi; }
        __syncthreads();
        if (tid == 0) {
            float fv = rv[0]; int fi = ri[0];
#pragma unroll
            for (int w = 1; w < 4; w++) {
                float ov = rv[w]; int oi = ri[w];
                if (ov > fv || (ov == fv && oi < fi)) { fv = ov; fi = oi; }
            }
            if (fv >= MATCH_IOU_T) {
                int j = fi;
                float s2 = s2w[j];
                float sc0 = mscore[i];
                float tot = __fadd_rn(sc0, s2);
#pragma unroll
                for (int cc = 0; cc < 4; cc++) {
                    float merged = __fdiv_rn(
                        __fadd_rn(__fmul_rn(a[cc], sc0), __fmul_rn(b2s[j * 4 + cc], s2)), tot);
                    mbox[i * 4 + cc] = merged;
                }
                mscore[i] = tot;
                used[j] = 1;
            }
        }
        __syncthreads();
    }
    for (int j = tid; j < N2; j += 256) valid2[j] = used[j] ? 0 : 1;
}

// K3: composite sort keys. Stable argsort(-where(valid,s,-1)) == ascending
// sort of ((~sortable_f32(val)) << 32) | index.
__global__ void k3_keys(const float* mscore, const float* s2w, const int* valid2, u64* keys) {
    int i = blockIdx.x * blockDim.x + threadIdx.x;
    if (i >= NT) return;
    float sc; int val;
    if (i < N1) { sc = mscore[i]; val = 1; }
    else        { sc = s2w[i - N1]; val = valid2[i - N1]; }
    float f = val ? sc : -1.0f;
    u32 u = __float_as_uint(f);
    u32 asc = (u >> 31) ? ~u : (u | 0x80000000u);
    keys[i] = (((u64)(~asc)) << 32) | (u32)i;
}

// K4: exact stable sort by rank-counting. Re-blocked: 384 blocks x 16 rows,
// key array staged once in 48KB LDS (L2 traffic /16 vs one-block-per-row).
__global__ void __launch_bounds__(256) k4_rank(const u64* keys, int* ord) {
    __shared__ u64 ks[NT];     // 48 KB
    __shared__ int cnts[16];
    int tid = threadIdx.x;
    for (int t = tid; t < NT; t += 256) ks[t] = keys[t];
    if (tid < 16) cnts[tid] = 0;
    __syncthreads();
    int i0 = blockIdx.x * 16;
    u64 myk[16];
#pragma unroll
    for (int g = 0; g < 16; g++) myk[g] = ks[i0 + g];
    int local[16];
#pragma unroll
    for (int g = 0; g < 16; g++) local[g] = 0;
    for (int j = tid; j < NT; j += 256) {
        u64 kj = ks[j];
#pragma unroll
        for (int g = 0; g < 16; g++) local[g] += (kj < myk[g]) ? 1 : 0;
    }
#pragma unroll
    for (int g = 0; g < 16; g++) {
        int v = local[g];
#pragma unroll
        for (int s = 32; s > 0; s >>= 1) v += __shfl_down(v, s, 64);
        if ((tid & 63) == 0) atomicAdd(&cnts[g], v);
    }
    __syncthreads();
    if (tid < 16) ord[cnts[tid]] = i0 + tid;
}

// K5: gather into sorted order; write boxes/labels/scores outputs.
__global__ void k5_gather(const int* ord, const float* mbox, const float* mscore,
                          const float* b2n, const float* s2w, const int* valid2,
                          const int* yl, const int* fl,
                          float* sboxn, int* slab, int* svalid, float* out) {
    int k = blockIdx.x * blockDim.x + threadIdx.x;
    if (k >= NT) return;
    int i = ord[k];
    float b[4]; int lab; float sc; int val;
    if (i < N1) {
#pragma unroll
        for (int c = 0; c < 4; c++) b[c] = mbox[i * 4 + c];
        lab = yl[i]; sc = mscore[i]; val = 1;
    } else {
        int j = i - N1;
#pragma unroll
        for (int c = 0; c < 4; c++) b[c] = b2n[j * 4 + c];
        lab = fl[j]; sc = s2w[j]; val = valid2[j];
    }
#pragma unroll
    for (int c = 0; c < 4; c++) {
        sboxn[k * 4 + c] = b[c];
        out[k * 4 + c] = __fmul_rn(b[c], IMG);
    }
    slab[k] = lab; svalid[k] = val;
    out[24576 + k] = (lab == 0) ? 2.0f : 1.0f;   // label_map[clip(l,0,1)]
    out[24576 + NT + k] = sc;                     // sorted scores
}

// K6: NMS candidate pairs (i<j, same label, IoU >= 0.95) -> atomic append.
__global__ void __launch_bounds__(256) k6_pairs(const float* sboxn, const int* slab,
                                                int* pcount, u64* pairs) {
    int i = blockIdx.x;
    int tid = threadIdx.x;
    float a[4] = {sboxn[i * 4], sboxn[i * 4 + 1], sboxn[i * 4 + 2], sboxn[i * 4 + 3]};
    int lab = slab[i];
    for (int j = i + 1 + tid; j < NT; j += 256) {
        if (slab[j] == lab) {
            float bb[4] = {sboxn[j * 4], sboxn[j * 4 + 1], sboxn[j * 4 + 2], sboxn[j * 4 + 3]};
            if (iou_f(a, bb) >= NMS_IOU_T) {
                int pos = atomicAdd(pcount, 1);
                if (pos < CAP) pairs[pos] = (((u64)(u32)i) << 32) | (u32)j;
            }
        }
    }
}

// K7: sort pairs (restores determinism after atomic append), then exact
// sequential suppression resolution; write keep mask. Bitonic is runtime-sized
// (np is ~tens; sorting 4096 sentinels was wasted work).
__global__ void __launch_bounds__(256) k7_resolve(const int* pcount, const u64* pairs,
                                                  const int* svalid, float* out) {
    __shared__ u64 pl[CAP];
    __shared__ unsigned char sup[NT];
    int tid = threadIdx.x;
    int np = *pcount;
    if (np > CAP) np = CAP;
    for (int t = tid; t < CAP; t += 256) pl[t] = (t < np) ? pairs[t] : ~0ULL;
    for (int k = tid; k < NT; k += 256) sup[k] = svalid[k] ? 0 : 1;
    __syncthreads();
    if (np > 0) {
        int m = 2;
        while (m < np) m <<= 1;
        for (int k2 = 2; k2 <= m; k2 <<= 1) {
            for (int jj = k2 >> 1; jj > 0; jj >>= 1) {
                for (int idx = tid; idx < m; idx += 256) {
                    int l = idx ^ jj;
                    if (l > idx) {
                        u64 A = pl[idx], B = pl[l];
                        bool up = ((idx & k2) == 0);
                        if (up ? (A > B) : (A < B)) { pl[idx] = B; pl[l] = A; }
                    }
                }
                __syncthreads();
            }
        }
        if (tid == 0) {
            for (int p = 0; p < np; p++) {
                u64 pr = pl[p];
                int i = (int)(pr >> 32);
                int j = (int)(pr & 0xffffffffu);
                if (!sup[i]) sup[j] = 1;
            }
        }
        __syncthreads();
    }
    for (int k = tid; k < NT; k += 256) out[24576 + 2 * NT + k] = sup[k] ? 0.0f : 1.0f;
}

extern "C" void kernel_launch(void* const* d_in, const int* in_sizes, int n_in,
                              void* d_out, int out_size, void* d_ws, size_t ws_size,
                              hipStream_t stream) {
    const float* yb = (const float*)d_in[0];
    const float* ys = (const float*)d_in[1];
    const int*   yl = (const int*)d_in[2];
    const float* fb = (const float*)d_in[3];
    const float* fs = (const float*)d_in[4];
    const int*   fl = (const int*)d_in[5];
    float* out = (float*)d_out;
    char* ws = (char*)d_ws;

    float* b2n    = (float*)(ws);            // 2048*4 f   = 32768 B
    float* s2w    = (float*)(ws + 32768);    // 2048 f     =  8192 B
    float* mbox   = (float*)(ws + 40960);    // 4096*4 f   = 65536 B
    float* mscore = (float*)(ws + 106496);   // 4096 f     = 16384 B
    int*   flag   = (int*)  (ws + 122880);   // 4096 i     = 16384 B
    int*   valid2 = (int*)  (ws + 139264);   // 2048 i     =  8192 B
    u64*   keys   = (u64*)  (ws + 147456);   // 6144 u64   = 49152 B
    int*   ord    = (int*)  (ws + 196608);   // 6144 i     = 24576 B
    float* sboxn  = (float*)(ws + 221184);   // 6144*4 f   = 98304 B
    int*   slab   = (int*)  (ws + 319488);   // 6144 i     = 24576 B
    int*   svalid = (int*)  (ws + 344064);   // 6144 i     = 24576 B
    int*   pcount = (int*)  (ws + 368640);   // 8 B
    u64*   pairs  = (u64*)  (ws + 368648);   // 4096 u64   = 32768 B  (end ~401 KB)

    hipLaunchKernelGGL(k0_prep,  dim3(32),   dim3(256), 0, stream, fb, fs, b2n, s2w, pcount);
    hipLaunchKernelGGL(k1_flag,  dim3(N1),   dim3(256), 0, stream, yb, ys, yl, fl, b2n, mbox, mscore, flag);
    hipLaunchKernelGGL(k2_match, dim3(1),    dim3(256), 0, stream, yl, fl, b2n, s2w, flag, mbox, mscore, valid2);
    hipLaunchKernelGGL(k3_keys,  dim3(24),   dim3(256), 0, stream, mscore, s2w, valid2, keys);
    hipLaunchKernelGGL(k4_rank,  dim3(NT/16),dim3(256), 0, stream, keys, ord);
    hipLaunchKernelGGL(k5_gather,dim3(24),   dim3(256), 0, stream, ord, mbox, mscore, b2n, s2w, valid2, yl, fl, sboxn, slab, svalid, out);
    hipLaunchKernelGGL(k6_pairs, dim3(NT),   dim3(256), 0, stream, sboxn, slab, pcount, pairs);
    hipLaunchKernelGGL(k7_resolve,dim3(1),   dim3(256), 0, stream, pcount, pairs, svalid, out);
}

// Round 7
// 72.209 us; speedup vs baseline: 6.4500x; 1.6510x over previous
//
#include <hip/hip_runtime.h>

typedef unsigned long long u64;
typedef unsigned int u32;

#define N1 4096
#define N2 2048
#define NT 6144
#define CAP 4096
#define MCAP 4096
#define IMG 1280.0f
#define MATCH_IOU_T 0.8f
#define NMS_IOU_T 0.95f

// IoU with exact op-order mirroring of the reference (no FMA contraction).
__device__ __forceinline__ float iou_f(const float* a, const float* b) {
    float x1 = fmaxf(a[0], b[0]);
    float y1 = fmaxf(a[1], b[1]);
    float x2 = fminf(a[2], b[2]);
    float y2 = fminf(a[3], b[3]);
    float dx = fmaxf(__fsub_rn(x2, x1), 0.0f);
    float dy = fmaxf(__fsub_rn(y2, y1), 0.0f);
    float inter = __fmul_rn(dx, dy);
    float a1 = __fmul_rn(__fsub_rn(a[2], a[0]), __fsub_rn(a[3], a[1]));
    float a2 = __fmul_rn(__fsub_rn(b[2], b[0]), __fsub_rn(b[3], b[1]));
    float den = __fsub_rn(__fadd_rn(a1, a2), inter);
    return __fdiv_rn(inter, den);
}

// K0: normalize frcnn boxes, weight scores, zero both pair counters.
__global__ void k0_prep(const float* fb, const float* fs, float* b2n, float* s2w,
                        int* pcount, int* mpcount) {
    int t = blockIdx.x * blockDim.x + threadIdx.x;
    if (t < N2 * 4) b2n[t] = __fdiv_rn(fb[t], IMG);
    if (t < N2)     s2w[t] = __fmul_rn(fs[t], 0.5f);
    if (t == 0)     { *pcount = 0; *mpcount = 0; }
}

// K1: per yolo box i, emit ALL candidate pairs (same label, unmasked IoU >= 0.8)
// with their exact IoU (masking by `used` only removes js, so any merge winner
// is in this set). Also write default (unmerged) mbox/mscore.
__global__ void __launch_bounds__(256) k1_flag(const float* yb, const float* ys,
                                               const int* yl, const int* fl,
                                               const float* b2n, float* mbox,
                                               float* mscore, int* mpcount,
                                               u64* mpk, float* mpi) {
    int i = blockIdx.x;
    int tid = threadIdx.x;
    float a[4];
#pragma unroll
    for (int c = 0; c < 4; c++) a[c] = __fdiv_rn(yb[i * 4 + c], IMG);
    int lab = yl[i];
    for (int j = tid; j < N2; j += 256) {
        if (fl[j] == lab) {
            float bb[4] = {b2n[j * 4], b2n[j * 4 + 1], b2n[j * 4 + 2], b2n[j * 4 + 3]};
            float v = iou_f(a, bb);
            if (v >= MATCH_IOU_T) {
                int pos = atomicAdd(mpcount, 1);
                if (pos < MCAP) { mpk[pos] = (((u64)(u32)i) << 32) | (u32)j; mpi[pos] = v; }
            }
        }
    }
    if (tid == 0) {
#pragma unroll
        for (int c = 0; c < 4; c++) mbox[i * 4 + c] = a[c];
        mscore[i] = __fmul_rn(ys[i], 0.5f);
    }
}

// K2: exact sequential greedy over the sparse candidate-pair list only.
// Sort (key,iou) by (i<<32)|j (i-ascending groups, j-ascending tie-break ==
// argmax lowest-index semantics); thread-0 walk picks per-i the strict-max
// unused iou (always >= 0.8 by construction => merge); parallel apply pass.
__global__ void __launch_bounds__(256) k2_match(const float* b2n, const float* s2w,
                                                const int* mpcount, const u64* mpk,
                                                const float* mpi, float* mbox,
                                                float* mscore, int* valid2) {
    __shared__ u64 pk[MCAP];            // 32 KB
    __shared__ float pv[MCAP];          // 16 KB
    __shared__ unsigned char dec[MCAP]; //  4 KB
    __shared__ unsigned char used[N2];  //  2 KB
    int tid = threadIdx.x;
    int np = *mpcount;
    if (np > MCAP) np = MCAP;
    for (int t = tid; t < MCAP; t += 256) {
        pk[t] = (t < np) ? mpk[t] : ~0ULL;
        pv[t] = (t < np) ? mpi[t] : 0.0f;
        dec[t] = 0;
    }
    for (int j = tid; j < N2; j += 256) used[j] = 0;
    __syncthreads();
    if (np > 0) {
        // runtime-sized bitonic sort of (pk, pv) by pk
        int m = 2;
        while (m < np) m <<= 1;
        for (int k2 = 2; k2 <= m; k2 <<= 1) {
            for (int jj = k2 >> 1; jj > 0; jj >>= 1) {
                for (int idx = tid; idx < m; idx += 256) {
                    int l = idx ^ jj;
                    if (l > idx) {
                        u64 A = pk[idx], B = pk[l];
                        bool up = ((idx & k2) == 0);
                        if (up ? (A > B) : (A < B)) {
                            pk[idx] = B; pk[l] = A;
                            float fA = pv[idx]; pv[idx] = pv[l]; pv[l] = fA;
                        }
                    }
                }
                __syncthreads();
            }
        }
        // serial greedy walk (np ~ hundreds; ~200 cy/pair)
        if (tid == 0) {
            int cur_i = -1, best_p = -1, best_j = -1;
            float best_v = -1.0f;
            for (int p = 0; p < np; p++) {
                u64 pr = pk[p];
                int i = (int)(pr >> 32);
                int j = (int)(pr & 0xffffffffu);
                if (i != cur_i) {
                    if (best_p >= 0) { dec[best_p] = 1; used[best_j] = 1; }
                    cur_i = i; best_p = -1; best_j = -1; best_v = -1.0f;
                }
                if (!used[j]) {
                    float v = pv[p];
                    if (v > best_v) { best_v = v; best_p = p; best_j = j; }
                }
            }
            if (best_p >= 0) { dec[best_p] = 1; used[best_j] = 1; }
        }
        __syncthreads();
        // parallel apply (at most one dec'd pair per i -> disjoint writes)
        for (int p = tid; p < np; p += 256) {
            if (dec[p]) {
                u64 pr = pk[p];
                int i = (int)(pr >> 32);
                int j = (int)(pr & 0xffffffffu);
                float s2 = s2w[j];
                float sc0 = mscore[i];
                float tot = __fadd_rn(sc0, s2);
#pragma unroll
                for (int cc = 0; cc < 4; cc++) {
                    float merged = __fdiv_rn(
                        __fadd_rn(__fmul_rn(mbox[i * 4 + cc], sc0),
                                  __fmul_rn(b2n[j * 4 + cc], s2)), tot);
                    mbox[i * 4 + cc] = merged;
                }
                mscore[i] = tot;
            }
        }
        __syncthreads();
    }
    for (int j = tid; j < N2; j += 256) valid2[j] = used[j] ? 0 : 1;
}

// K3: composite sort keys. Stable argsort(-where(valid,s,-1)) == ascending
// sort of ((~sortable_f32(val)) << 32) | index.
__global__ void k3_keys(const float* mscore, const float* s2w, const int* valid2, u64* keys) {
    int i = blockIdx.x * blockDim.x + threadIdx.x;
    if (i >= NT) return;
    float sc; int val;
    if (i < N1) { sc = mscore[i]; val = 1; }
    else        { sc = s2w[i - N1]; val = valid2[i - N1]; }
    float f = val ? sc : -1.0f;
    u32 u = __float_as_uint(f);
    u32 asc = (u >> 31) ? ~u : (u | 0x80000000u);
    keys[i] = (((u64)(~asc)) << 32) | (u32)i;
}

// K4: exact stable sort by rank-counting. 384 blocks x 16 rows, key array
// staged once in 48KB LDS.
__global__ void __launch_bounds__(256) k4_rank(const u64* keys, int* ord) {
    __shared__ u64 ks[NT];     // 48 KB
    __shared__ int cnts[16];
    int tid = threadIdx.x;
    for (int t = tid; t < NT; t += 256) ks[t] = keys[t];
    if (tid < 16) cnts[tid] = 0;
    __syncthreads();
    int i0 = blockIdx.x * 16;
    u64 myk[16];
#pragma unroll
    for (int g = 0; g < 16; g++) myk[g] = ks[i0 + g];
    int local[16];
#pragma unroll
    for (int g = 0; g < 16; g++) local[g] = 0;
    for (int j = tid; j < NT; j += 256) {
        u64 kj = ks[j];
#pragma unroll
        for (int g = 0; g < 16; g++) local[g] += (kj < myk[g]) ? 1 : 0;
    }
#pragma unroll
    for (int g = 0; g < 16; g++) {
        int v = local[g];
#pragma unroll
        for (int s = 32; s > 0; s >>= 1) v += __shfl_down(v, s, 64);
        if ((tid & 63) == 0) atomicAdd(&cnts[g], v);
    }
    __syncthreads();
    if (tid < 16) ord[cnts[tid]] = i0 + tid;
}

// K5: gather into sorted order; write boxes/labels/scores outputs.
__global__ void k5_gather(const int* ord, const float* mbox, const float* mscore,
                          const float* b2n, const float* s2w, const int* valid2,
                          const int* yl, const int* fl,
                          float* sboxn, int* slab, int* svalid, float* out) {
    int k = blockIdx.x * blockDim.x + threadIdx.x;
    if (k >= NT) return;
    int i = ord[k];
    float b[4]; int lab; float sc; int val;
    if (i < N1) {
#pragma unroll
        for (int c = 0; c < 4; c++) b[c] = mbox[i * 4 + c];
        lab = yl[i]; sc = mscore[i]; val = 1;
    } else {
        int j = i - N1;
#pragma unroll
        for (int c = 0; c < 4; c++) b[c] = b2n[j * 4 + c];
        lab = fl[j]; sc = s2w[j]; val = valid2[j];
    }
#pragma unroll
    for (int c = 0; c < 4; c++) {
        sboxn[k * 4 + c] = b[c];
        out[k * 4 + c] = __fmul_rn(b[c], IMG);
    }
    slab[k] = lab; svalid[k] = val;
    out[24576 + k] = (lab == 0) ? 2.0f : 1.0f;   // label_map[clip(l,0,1)]
    out[24576 + NT + k] = sc;                     // sorted scores
}

// K6: NMS candidate pairs (i<j, same label, IoU >= 0.95) -> atomic append.
__global__ void __launch_bounds__(256) k6_pairs(const float* sboxn, const int* slab,
                                                int* pcount, u64* pairs) {
    int i = blockIdx.x;
    int tid = threadIdx.x;
    float a[4] = {sboxn[i * 4], sboxn[i * 4 + 1], sboxn[i * 4 + 2], sboxn[i * 4 + 3]};
    int lab = slab[i];
    for (int j = i + 1 + tid; j < NT; j += 256) {
        if (slab[j] == lab) {
            float bb[4] = {sboxn[j * 4], sboxn[j * 4 + 1], sboxn[j * 4 + 2], sboxn[j * 4 + 3]};
            if (iou_f(a, bb) >= NMS_IOU_T) {
                int pos = atomicAdd(pcount, 1);
                if (pos < CAP) pairs[pos] = (((u64)(u32)i) << 32) | (u32)j;
            }
        }
    }
}

// K7: sort pairs (restores determinism after atomic append), then exact
// sequential suppression resolution; write keep mask. Runtime-sized bitonic.
__global__ void __launch_bounds__(256) k7_resolve(const int* pcount, const u64* pairs,
                                                  const int* svalid, float* out) {
    __shared__ u64 pl[CAP];
    __shared__ unsigned char sup[NT];
    int tid = threadIdx.x;
    int np = *pcount;
    if (np > CAP) np = CAP;
    for (int t = tid; t < CAP; t += 256) pl[t] = (t < np) ? pairs[t] : ~0ULL;
    for (int k = tid; k < NT; k += 256) sup[k] = svalid[k] ? 0 : 1;
    __syncthreads();
    if (np > 0) {
        int m = 2;
        while (m < np) m <<= 1;
        for (int k2 = 2; k2 <= m; k2 <<= 1) {
            for (int jj = k2 >> 1; jj > 0; jj >>= 1) {
                for (int idx = tid; idx < m; idx += 256) {
                    int l = idx ^ jj;
                    if (l > idx) {
                        u64 A = pl[idx], B = pl[l];
                        bool up = ((idx & k2) == 0);
                        if (up ? (A > B) : (A < B)) { pl[idx] = B; pl[l] = A; }
                    }
                }
                __syncthreads();
            }
        }
        if (tid == 0) {
            for (int p = 0; p < np; p++) {
                u64 pr = pl[p];
                int i = (int)(pr >> 32);
                int j = (int)(pr & 0xffffffffu);
                if (!sup[i]) sup[j] = 1;
            }
        }
        __syncthreads();
    }
    for (int k = tid; k < NT; k += 256) out[24576 + 2 * NT + k] = sup[k] ? 0.0f : 1.0f;
}

extern "C" void kernel_launch(void* const* d_in, const int* in_sizes, int n_in,
                              void* d_out, int out_size, void* d_ws, size_t ws_size,
                              hipStream_t stream) {
    const float* yb = (const float*)d_in[0];
    const float* ys = (const float*)d_in[1];
    const int*   yl = (const int*)d_in[2];
    const float* fb = (const float*)d_in[3];
    const float* fs = (const float*)d_in[4];
    const int*   fl = (const int*)d_in[5];
    float* out = (float*)d_out;
    char* ws = (char*)d_ws;

    float* b2n     = (float*)(ws);            // 2048*4 f   = 32768 B
    float* s2w     = (float*)(ws + 32768);    // 2048 f     =  8192 B
    float* mbox    = (float*)(ws + 40960);    // 4096*4 f   = 65536 B
    float* mscore  = (float*)(ws + 106496);   // 4096 f     = 16384 B
    int*   valid2  = (int*)  (ws + 122880);   // 2048 i     =  8192 B
    u64*   keys    = (u64*)  (ws + 131072);   // 6144 u64   = 49152 B
    int*   ord     = (int*)  (ws + 180224);   // 6144 i     = 24576 B
    float* sboxn   = (float*)(ws + 204800);   // 6144*4 f   = 98304 B
    int*   slab    = (int*)  (ws + 303104);   // 6144 i     = 24576 B
    int*   svalid  = (int*)  (ws + 327680);   // 6144 i     = 24576 B
    int*   pcount  = (int*)  (ws + 352256);   // 8 B
    int*   mpcount = (int*)  (ws + 352264);   // 8 B
    u64*   mpk     = (u64*)  (ws + 352272);   // 4096 u64   = 32768 B
    float* mpi     = (float*)(ws + 385040);   // 4096 f     = 16384 B
    u64*   pairs   = (u64*)  (ws + 401424);   // 4096 u64   = 32768 B (end ~434 KB)

    hipLaunchKernelGGL(k0_prep,  dim3(32),   dim3(256), 0, stream, fb, fs, b2n, s2w, pcount, mpcount);
    hipLaunchKernelGGL(k1_flag,  dim3(N1),   dim3(256), 0, stream, yb, ys, yl, fl, b2n, mbox, mscore, mpcount, mpk, mpi);
    hipLaunchKernelGGL(k2_match, dim3(1),    dim3(256), 0, stream, b2n, s2w, mpcount, mpk, mpi, mbox, mscore, valid2);
    hipLaunchKernelGGL(k3_keys,  dim3(24),   dim3(256), 0, stream, mscore, s2w, valid2, keys);
    hipLaunchKernelGGL(k4_rank,  dim3(NT/16),dim3(256), 0, stream, keys, ord);
    hipLaunchKernelGGL(k5_gather,dim3(24),   dim3(256), 0, stream, ord, mbox, mscore, b2n, s2w, valid2, yl, fl, sboxn, slab, svalid, out);
    hipLaunchKernelGGL(k6_pairs, dim3(NT),   dim3(256), 0, stream, sboxn, slab, pcount, pairs);
    hipLaunchKernelGGL(k7_resolve,dim3(1),   dim3(256), 0, stream, pcount, pairs, svalid, out);
}